// Round 5
// baseline (341.729 us; speedup 1.0000x reference)
//
#include <hip/hip_runtime.h>
#include <hip/hip_fp16.h>
#include <math.h>

#define BATCH 16
#define CIN   128
#define LIN   8192
#define COUT  128
#define LOUT  16384
#define KEXP  768          // 2 shift-halves * (3 powers * 128 channels)
#define NT    256          // i-tile width (doubled: halves per-output A-frag L2 traffic)
#define NTILES (LIN/NT)    // 32
#define PCOLS 258          // i0-1 .. i0+256 inclusive
#define PCPAD 136          // halfwords per col; 272B stride, 16B aligned
#define PSZ   (PCOLS*PCPAD)  // one plane: 35088 halfs = 70176 B

typedef _Float16 f16x8 __attribute__((ext_vector_type(8)));
typedef float    f32x4 __attribute__((ext_vector_type(4)));

// ---------------- weight prep: fold taps, cast fp16, PHASE-MAJOR frag swizzle ----------------
// K-step order ks = q*8 + sh*4 + cb_idx  (q = power, sh = shift-half, cb = 32-chan group)
// Element (co,k) -> WE[((mtile*24 + ks)*64 + quad*16 + l15)*8 + j]
// so one A-frag load = uniform base + lane*16B (contiguous 1KB).
__global__ void prep_weights(const float* __restrict__ W,
                             _Float16* __restrict__ WE,
                             _Float16* __restrict__ WO) {
  int idx = blockIdx.x * 256 + threadIdx.x;       // 128*768 total
  int co = idx / KEXP;
  int k  = idx % KEXP;
  int sh = (k >= 384) ? 1 : 0;
  int cq = k - 384 * sh;                          // 384 is NOT a power of two
  const float* w = W + ((size_t)co * 384 + cq) * 3;
  float we, wo;
  if (sh == 0) { we = w[0];        wo = w[0] + w[1]; }
  else         { we = w[1] + w[2]; wo = w[2];        }
  int q  = cq >> 7;            // power plane 0..2
  int c  = cq & 127;           // channel within plane
  int ks = q * 8 + sh * 4 + (c >> 5);
  int kk = c & 31, quad = kk >> 3, j = kk & 7;
  int mtile = co >> 4, l15 = co & 15;
  size_t off = ((size_t)((mtile * 24 + ks) * 64) + quad * 16 + l15) * 8 + j;
  WE[off] = (_Float16)we;
  WO[off] = (_Float16)wo;
}

// ---------------- fused conv GEMM: NT=256, 8 waves = 2m x 2n x {E,O}, dbuf planes ----------------
__launch_bounds__(512, 2)
__global__ void conv_gemm(const float* __restrict__ x,
                          const _Float16* __restrict__ WE,
                          const _Float16* __restrict__ WO,
                          float* __restrict__ out,
                          float* __restrict__ stats) {
  extern __shared__ char smem[];
  float*    sstats = (float*)smem;                   // [128][2]
  _Float16* P0     = (_Float16*)(smem + 1024);       // plane buffer A
  _Float16* P1     = P0 + PSZ;                       // plane buffer B

  const int tile = blockIdx.x;        // 0..31
  const int b    = blockIdx.y;        // 0..15
  const int i0   = tile * NT;
  const int t    = threadIdx.x;
  const int lane = t & 63;
  const int wave = t >> 6;            // 0..7
  const int p    = wave >> 1;         // 2x2 over (m,n)
  const int isO  = wave & 1;          // 0=even outputs, 1=odd outputs
  const int wm   = p >> 1, wn = p & 1;
  const int l15  = lane & 15, quad = lane >> 4;
  const int kl   = quad * 8;

  if (t < 128) { sstats[2 * t] = 0.f; sstats[2 * t + 1] = 0.f; }

  const float* xb = x + (size_t)b * CIN * LIN;
  const _Float16* Wsel = isO ? WO : WE;

  f32x4 acc[4][8];
  const f32x4 zero = {0.f, 0.f, 0.f, 0.f};
#pragma unroll
  for (int fm = 0; fm < 4; ++fm)
#pragma unroll
    for (int fn = 0; fn < 8; ++fn) acc[fm][fn] = zero;

  // build plane holding x^qp into dst
  auto build = [&](int qp, _Float16* dst) {
    for (int it = 0; it < 9; ++it) {
      int idx = it * 512 + t;
      if (idx < PCOLS * 16) {
        int g   = idx / PCOLS;                 // 8-channel group 0..15
        int col = idx - g * PCOLS;             // consecutive t -> consecutive col (coalesced)
        int c8  = g * 8;
        int gi  = i0 - 1 + col;
        bool ok = (gi >= 0 && gi < LIN);
        f16x8 w;
#pragma unroll
        for (int j = 0; j < 8; ++j) {
          float v = ok ? xb[(size_t)(c8 + j) * LIN + gi] : 0.f;
          float pv = (qp == 1) ? v : ((qp == 2) ? v * v : v * v * v);
          w[j] = (_Float16)pv;
        }
        *(f16x8*)(dst + col * PCPAD + c8) = w;
      }
    }
  };

  // 8 k-steps on plane pl for power-index q
  auto ksteps = [&](int q, const _Float16* pl) {
#pragma unroll
    for (int s = 0; s < 8; ++s) {
      const int cb   = (s & 3) * 32;
      const int shft = (s >> 2) + isO;
      const _Float16* pb = pl + cb + kl;
      f16x8 af[4], bf[8];
#pragma unroll
      for (int fm = 0; fm < 4; ++fm) {
        int mt = wm * 4 + fm;
        af[fm] = *(const f16x8*)(Wsel + ((size_t)((mt * 24 + q * 8 + s) * 64) + lane) * 8);
      }
#pragma unroll
      for (int fn = 0; fn < 8; ++fn) {
        int colB = wn * 128 + fn * 16 + l15 + shft;
        bf[fn] = *(const f16x8*)(pb + colB * PCPAD);
      }
#pragma unroll
      for (int fm = 0; fm < 4; ++fm)
#pragma unroll
        for (int fn = 0; fn < 8; ++fn)
          acc[fm][fn] = __builtin_amdgcn_mfma_f32_16x16x32_f16(af[fm], bf[fn], acc[fm][fn], 0, 0, 0);
    }
  };

  build(1, P0);
  __syncthreads();
  build(2, P1);        // overlaps with q=0 compute (indep of P0)
  ksteps(0, P0);
  __syncthreads();
  build(3, P0);        // overlaps with q=1 compute (P0's readers done)
  ksteps(1, P1);
  __syncthreads();
  ksteps(2, P0);
  __syncthreads();

  // --- epilogue: per-wave stats + direct interleave-by-wave stores ---
  // C/D layout: n = lane&15, m = quad*4 + r
  float* orow_base = out + (size_t)b * COUT * LOUT + isO;
#pragma unroll
  for (int fm = 0; fm < 4; ++fm) {
#pragma unroll
    for (int r = 0; r < 4; ++r) {
      float s1 = 0.f, s2 = 0.f;
#pragma unroll
      for (int fn = 0; fn < 8; ++fn) {
        float v = acc[fm][fn][r];
        s1 += v;
        s2 += v * v;
      }
#pragma unroll
      for (int off = 8; off >= 1; off >>= 1) {   // reduce across the 16 n-lanes
        s1 += __shfl_xor(s1, off, 64);
        s2 += __shfl_xor(s2, off, 64);
      }
      int co = wm * 64 + fm * 16 + quad * 4 + r;
      if (l15 == 0) {
        atomicAdd(&sstats[2 * co], s1);
        atomicAdd(&sstats[2 * co + 1], s2);
      }
      float* orow = orow_base + (size_t)co * LOUT;
#pragma unroll
      for (int fn = 0; fn < 8; ++fn) {
        int n = i0 + wn * 128 + fn * 16 + l15;
        orow[2 * n] = acc[fm][fn][r];            // E/O waves write complementary 4B-interleave
      }
    }
  }
  __syncthreads();
  if (t < 128) {
    atomicAdd(&stats[((size_t)b * COUT + t) * 2],     sstats[2 * t]);
    atomicAdd(&stats[((size_t)b * COUT + t) * 2 + 1], sstats[2 * t + 1]);
  }
}

// ---------------- instance norm + tanh, in place ----------------
__device__ inline float tanh_fast(float z) {
  float e = __expf(2.f * z);
  return 1.f - 2.f * __builtin_amdgcn_rcpf(e + 1.f);
}

__global__ void norm_tanh(float* __restrict__ out, const float* __restrict__ stats) {
  int row = blockIdx.x;                         // b*128 + co
  float s1 = stats[2 * row], s2 = stats[2 * row + 1];
  const float invN = 1.f / (float)LOUT;
  float mean = s1 * invN;
  float var  = fmaxf(s2 * invN - mean * mean, 0.f);
  float inv  = rsqrtf(var + 1e-5f);
  float c0   = -mean * inv;
  float4* p = (float4*)(out + (size_t)row * LOUT);
  for (int i = threadIdx.x; i < LOUT / 4; i += 256) {
    float4 v = p[i];
    v.x = tanh_fast(fmaf(v.x, inv, c0));
    v.y = tanh_fast(fmaf(v.y, inv, c0));
    v.z = tanh_fast(fmaf(v.z, inv, c0));
    v.w = tanh_fast(fmaf(v.w, inv, c0));
    p[i] = v;
  }
}

extern "C" void kernel_launch(void* const* d_in, const int* in_sizes, int n_in,
                              void* d_out, int out_size, void* d_ws, size_t ws_size,
                              hipStream_t stream) {
  const float* x = (const float*)d_in[0];
  const float* W = (const float*)d_in[1];
  // bias (d_in[2]) is exactly cancelled by InstanceNorm -> unused
  float* out = (float*)d_out;

  float*    stats = (float*)d_ws;
  _Float16* WE    = (_Float16*)((char*)d_ws + 16384);
  _Float16* WO    = WE + (size_t)COUT * KEXP;

  hipMemsetAsync(d_ws, 0, 16384, stream);
  prep_weights<<<dim3((COUT * KEXP) / 256), dim3(256), 0, stream>>>(W, WE, WO);

  size_t shmem = 1024 + (size_t)2 * PSZ * 2;   // 141,376 B: dbuf planes, 1 block/CU (reg-limited anyway)
  hipFuncSetAttribute(reinterpret_cast<const void*>(conv_gemm),
                      hipFuncAttributeMaxDynamicSharedMemorySize, (int)shmem);
  conv_gemm<<<dim3(NTILES, BATCH), dim3(512), shmem, stream>>>(x, WE, WO, out, stats);

  norm_tanh<<<dim3(BATCH * COUT), dim3(256), 0, stream>>>(out, stats);
}